// Round 8
// baseline (428.927 us; speedup 1.0000x reference)
//
#include <hip/hip_runtime.h>

// Swin window attention, fully fused, persistent blocks (1 block/CU, 256
// blocks, 16-batch loop per block).
//
// R6 change (from R5 @ 162us kernel; MfmaUtil 11%, VALUBusy 30%, HBM 17%,
// 10.1us/iter vs ~4us work -- serial phase chain is the remaining cost):
// PRODUCER/CONSUMER WAVE SPECIALIZATION. Waves 0-7 compute QKV(b+1) into
// double-buffered q/k/v LDS while waves 8-15 run attention+outproj+store
// for batch b. 3 block barriers per slot (same count as R5) but the two
// pipelines overlap instead of serializing.
//   - x staged in producer REGISTERS (8 frags = 32 VGPR/lane; each producer
//     wave has fixed mh = wid&1 so needs only 2 of 4 m-tiles) -> xs LDS gone.
//   - P-scratch per consumer wave (8 x [16][72] bf16 = 18.4KB, same-wave
//     write->read only, ordered by lgkmcnt(0)).
//   - osr (f32 out-proj staging) unions with the just-consumed q/k buffer.
//   - all float->bf16 via native casts -> compiler emits v_cvt_pk_bf16_f32
//     (VALU cut; identical RNE rounding).
// LDS: qk dbuf 69632 + v dbuf 36864 + Ps 18432 + oa 17408 + bias 16640
//      = 158976 B (155.2 KiB <= 160 KiB).
// Slot layout (b = -1..15; producers act when b+1<16, consumers when b>=0):
//   chunk0: P: x-frag loads + QKV n-tiles 0-7 (q)   | C: QK^T+softmax+PV -> oa
//   bar    (q/k/v[wbuf] vs attn on [rbuf] disjoint; oa ready for ph5)
//   chunk1: P: QKV n-tiles 8-15 (k)                 | C: out-proj -> osr
//   bar    (osr ready for store pass)
//   chunk2: P: QKV n-tiles 16-23 (v)                | C: coalesced f32 stores
//   bar    (slot boundary: qkv[wbuf] complete -> readable next slot)
// Hazard audit: every producer-write/consumer-read pair crosses the slot
// barrier; osr writes (into qk[rbuf]) happen after all consumer q/k reads
// (chunk0->bar); next-slot producer writes to qk[rbuf] cross the slot bar.
// (4th resubmission: four GPUAcquisitionTimeouts in a row -- this source
// has never executed; hand-off, coverage, and union lifetimes re-audited
// again, no defects found; unchanged to preserve attribution.)
//
// MFMA 16x16x32 bf16 fragment layouts (HW-verified per guide m89/m91/m120):
//   A[m][k]: m = lane&15, k = (lane>>4)*8 + j   (8 contiguous bf16 = 16B)
//   B[k][n]: n = lane&15, k = (lane>>4)*8 + j
//   D[m][n]: n = lane&15, m = (lane>>4)*4 + reg

typedef __bf16 bf16x8 __attribute__((ext_vector_type(8)));
typedef short  s16x8  __attribute__((ext_vector_type(8)));
typedef float  f32x4  __attribute__((ext_vector_type(4)));

static __device__ __forceinline__ unsigned short f2bf(float f) {
  __bf16 h = (__bf16)f;                      // RNE; compiler emits cvt_pk pairs
  return __builtin_bit_cast(unsigned short, h);
}
static __device__ __forceinline__ s16x8 cvt8(float4 lo, float4 hi) {
  s16x8 r;
  r[0] = (short)f2bf(lo.x); r[1] = (short)f2bf(lo.y);
  r[2] = (short)f2bf(lo.z); r[3] = (short)f2bf(lo.w);
  r[4] = (short)f2bf(hi.x); r[5] = (short)f2bf(hi.y);
  r[6] = (short)f2bf(hi.z); r[7] = (short)f2bf(hi.w);
  return r;
}
static __device__ __forceinline__ f32x4 mfma16(s16x8 a, s16x8 b, f32x4 c) {
  return __builtin_amdgcn_mfma_f32_16x16x32_bf16(
      __builtin_bit_cast(bf16x8, a), __builtin_bit_cast(bf16x8, b), c, 0, 0, 0);
}
// LDS-only barrier: orders ds ops across waves without draining vmcnt.
static __device__ __forceinline__ void bar_lds() {
  __builtin_amdgcn_sched_barrier(0);
  asm volatile("s_waitcnt lgkmcnt(0)" ::: "memory");
  __builtin_amdgcn_s_barrier();
  __builtin_amdgcn_sched_barrier(0);
}

// ---------------- prep: transpose + bf16-cast weights into workspace --------
__global__ void prep_weights(const float* __restrict__ wqkv,
                             const float* __restrict__ wout,
                             unsigned short* __restrict__ wqkvT,
                             unsigned short* __restrict__ woutT) {
  int idx = blockIdx.x * blockDim.x + threadIdx.x;
  const int total1 = 384 * 128;
  if (idx < total1) {
    int n = idx >> 7, k = idx & 127;
    wqkvT[idx] = f2bf(wqkv[k * 384 + n]);
  } else {
    int i2 = idx - total1;
    int n = i2 >> 7, k = i2 & 127;
    woutT[i2] = f2bf(wout[k * 128 + n]);
  }
}

// ---------------- LDS layout ------------------------------------------------
//   qk0: q0 [64][136] @ 0,     k0 [64][136] @ 17408    (34816 B)
//   qk1: q1 @ 34816,           k1 @ 52224               (34816 B)
//   v0  [128][72] @ 69632 (18432), v1 @ 88064 (18432)
//   Ps  8 x [16][72] bf16 @ 106496 (18432)   per-consumer-wave P scratch
//   oa  [64][136] bf16 @ 124928 (17408)
//   bias[64][65] f32 @ 142336 (16640)
//   osr (f32 [64][132] = 33792) unions with qk[rbuf] (34816) each slot.
#define OFF_V0  69632
#define OFF_PS  106496
#define OFF_OA  124928
#define OFF_BI  142336
#define SMEM_SZ 158976

#define BATCH_STRIDE (128 * 128 * 128)   // floats per batch image

template <int KIND>   // 0=q, 1=k, 2=v
static __device__ __forceinline__ void prod_task(
    int nt, const s16x8 (&xf)[2][4], const unsigned short* __restrict__ wqkvT,
    unsigned short* qw, unsigned short* kw, unsigned short* vw,
    int ln15, int quad, int m_sub, int mh) {
  const int n = nt * 16 + ln15;
  const unsigned short* wp = wqkvT + n * 128 + quad * 8;
  s16x8 bfr[4];
#pragma unroll
  for (int ks = 0; ks < 4; ++ks) bfr[ks] = *(const s16x8*)(wp + ks * 32);
#pragma unroll
  for (int mi = 0; mi < 2; ++mi) {
    f32x4 acc = {0.f, 0.f, 0.f, 0.f};
#pragma unroll
    for (int ks = 0; ks < 4; ++ks) acc = mfma16(xf[mi][ks], bfr[ks], acc);
    const int tok0 = (mh * 2 + mi) * 16 + m_sub;
    if constexpr (KIND == 0) {
#pragma unroll
      for (int r = 0; r < 4; ++r) qw[(tok0 + r) * 136 + n] = f2bf(acc[r]);
    } else if constexpr (KIND == 1) {
      const int nn = n - 128;
#pragma unroll
      for (int r = 0; r < 4; ++r) kw[(tok0 + r) * 136 + nn] = f2bf(acc[r]);
    } else {
      const int nn = n - 256;
      ushort4 pk;
      pk.x = f2bf(acc[0]); pk.y = f2bf(acc[1]);
      pk.z = f2bf(acc[2]); pk.w = f2bf(acc[3]);
      *(ushort4*)(vw + nn * 72 + tok0) = pk;   // v transposed [ch][tok]
    }
  }
}

__global__ __launch_bounds__(1024, 4)
void swin_fused(const float* __restrict__ x,
                const unsigned short* __restrict__ wqkvT,
                const unsigned short* __restrict__ woutT,
                const float* __restrict__ b_out,
                const float* __restrict__ pe,     // [15][15]
                const float* __restrict__ ulm,    // [64][64]
                const float* __restrict__ lrm,    // [64][64]
                float* __restrict__ out) {
  __shared__ __align__(16) unsigned char smem[SMEM_SZ];
  unsigned short* Ps_base = (unsigned short*)(smem + OFF_PS);
  unsigned short* oa_s    = (unsigned short*)(smem + OFF_OA);
  float*          bias_s  = (float*)(smem + OFF_BI);

  const int tid  = threadIdx.x;
  const int lane = tid & 63;
  const int wave = tid >> 6;        // 0..15
  const int ln15 = lane & 15;
  const int quad = lane >> 4;
  const int m_sub = quad << 2;

  const int wh = blockIdx.x >> 4, ww = blockIdx.x & 15;
  const bool is_prod = (wave < 8);
  const int wid  = wave & 7;        // producer id
  const int cwid = wave - 8;        // consumer id (valid when !is_prod)

  // ---- producer constants: fixed mh; per-lane x row offsets (2 m-tiles) ----
  const int mh = wid & 1;
  int rowoff[2];
#pragma unroll
  for (int mi = 0; mi < 2; ++mi) {
    int tok = (mh * 2 + mi) * 16 + ln15;
    int gi = ((wh << 3) + (tok >> 3) + 4) & 127;
    int gj = ((ww << 3) + (tok & 7) + 4) & 127;
    rowoff[mi] = (gi * 128 + gj) * 128;
  }

  // ---- consumer constants: store-pass addresses (4 float4 per thread) ----
  int off6[4], l6[4];
  if (!is_prod) {
    const int ct = cwid * 64 + lane;            // 0..511
#pragma unroll
    for (int k = 0; k < 4; ++k) {
      int item = ct + 512 * k;                  // 0..2047
      int tok = item >> 5, c4i = item & 31;
      int gi = ((wh << 3) + (tok >> 3) + 4) & 127;
      int gj = ((ww << 3) + (tok & 7) + 4) & 127;
      off6[k] = (gi * 128 + gj) * 128 + c4i * 4;
      l6[k] = tok * 132 + c4i * 4;
    }
  }

  // ---- prologue: build bias table once (all waves) ----
  {
    const bool has_ul = (wh == 15), has_lr = (ww == 15);
#pragma unroll
    for (int it = 0; it < 4; ++it) {
      int t = tid + it * 1024;                  // 4096 bias entries
      int i = t >> 6, j = t & 63;
      int r0 = (j >> 3) - (i >> 3) + 7;
      int r1 = (j & 7) - (i & 7) + 7;
      float bsum = pe[r0 * 15 + r1];
      if (has_ul) bsum += ulm[t];
      if (has_lr) bsum += lrm[t];
      bias_s[i * 65 + j] = bsum;
    }
  }
  __syncthreads();

  int wbuf = 1;
  for (int b = -1; b < 16; ++b) {
    const int rbuf = wbuf ^ 1;
    unsigned short* qw = (unsigned short*)(smem + wbuf * 34816);
    unsigned short* kw = qw + 8704;
    unsigned short* vw = (unsigned short*)(smem + OFF_V0 + wbuf * 18432);
    unsigned short* qr = (unsigned short*)(smem + rbuf * 34816);
    unsigned short* kr = qr + 8704;
    unsigned short* vr = (unsigned short*)(smem + OFF_V0 + rbuf * 18432);
    float*          osr = (float*)(smem + rbuf * 34816);   // union with qk[rbuf]

    const int nb = b + 1;
    const bool do_p = is_prod && (nb < 16);
    const bool do_c = (!is_prod) && (b >= 0);

    // ---- chunk 0: producers load x-frags + q n-tiles | consumers attn ----
    s16x8 xf[2][4];
    if (do_p) {
      const float* xb = x + (long)nb * BATCH_STRIDE;
#pragma unroll
      for (int mi = 0; mi < 2; ++mi)
#pragma unroll
        for (int ks = 0; ks < 4; ++ks) {
          const float* p = xb + rowoff[mi] + ks * 32 + quad * 8;
          float4 lo = *(const float4*)p;
          float4 hi = *(const float4*)(p + 4);
          xf[mi][ks] = cvt8(lo, hi);
        }
      prod_task<0>(wid >> 1,     xf, wqkvT, qw, kw, vw, ln15, quad, m_sub, mh);
      prod_task<0>((wid >> 1)+4, xf, wqkvT, qw, kw, vw, ln15, quad, m_sub, mh);
    } else if (do_c) {
      // QK^T + bias -> register softmax -> P (per-wave scratch) -> PV -> oa
      unsigned short* Ps = Ps_base + cwid * 1152;     // [16][72]
      const int mt = cwid & 3;
      const int tok0 = mt * 16 + m_sub;
      const float scale = 0.17677669529663687f;       // 32^-0.5
#pragma unroll
      for (int i = 0; i < 2; ++i) {
        const int h = (cwid >> 2) + 2 * i;
        s16x8 qf = *(const s16x8*)(qr + (mt * 16 + ln15) * 136 + h * 32 + quad * 8);
        f32x4 sv[4];
#pragma unroll
        for (int nt = 0; nt < 4; ++nt) {
          s16x8 kf = *(const s16x8*)(kr + (nt * 16 + ln15) * 136 + h * 32 + quad * 8);
          f32x4 acc = {0.f, 0.f, 0.f, 0.f};
          acc = mfma16(qf, kf, acc);
          int nn = nt * 16 + ln15;
#pragma unroll
          for (int r = 0; r < 4; ++r)
            sv[nt][r] = acc[r] * scale + bias_s[(tok0 + r) * 65 + nn];
        }
        float rinv[4];
#pragma unroll
        for (int r = 0; r < 4; ++r) {
          float m0 = fmaxf(fmaxf(sv[0][r], sv[1][r]), fmaxf(sv[2][r], sv[3][r]));
          m0 = fmaxf(m0, __shfl_xor(m0, 1));
          m0 = fmaxf(m0, __shfl_xor(m0, 2));
          m0 = fmaxf(m0, __shfl_xor(m0, 4));
          m0 = fmaxf(m0, __shfl_xor(m0, 8));
          float s0 = 0.f;
#pragma unroll
          for (int nt = 0; nt < 4; ++nt) {
            float e = __expf(sv[nt][r] - m0);
            sv[nt][r] = e;
            s0 += e;
          }
          s0 += __shfl_xor(s0, 1);
          s0 += __shfl_xor(s0, 2);
          s0 += __shfl_xor(s0, 4);
          s0 += __shfl_xor(s0, 8);
          rinv[r] = 1.0f / s0;
        }
#pragma unroll
        for (int nt = 0; nt < 4; ++nt) {
          int nn = nt * 16 + ln15;
#pragma unroll
          for (int r = 0; r < 4; ++r)
            Ps[(m_sub + r) * 72 + nn] = f2bf(sv[nt][r] * rinv[r]);
        }
        // same-wave LDS RAW: wave-level drain only (rule 18 fence)
        asm volatile("s_waitcnt lgkmcnt(0)" ::: "memory");
        __builtin_amdgcn_sched_barrier(0);
        s16x8 pfr[2];
#pragma unroll
        for (int ks = 0; ks < 2; ++ks)
          pfr[ks] = *(const s16x8*)(Ps + ln15 * 72 + ks * 32 + quad * 8);
#pragma unroll
        for (int nt2 = 0; nt2 < 2; ++nt2) {
          f32x4 acc = {0.f, 0.f, 0.f, 0.f};
#pragma unroll
          for (int ks = 0; ks < 2; ++ks) {
            s16x8 vf = *(const s16x8*)(vr + (h * 32 + nt2 * 16 + ln15) * 72 + ks * 32 + quad * 8);
            acc = mfma16(pfr[ks], vf, acc);
          }
          int n = h * 32 + nt2 * 16 + ln15;
#pragma unroll
          for (int r = 0; r < 4; ++r)
            oa_s[(tok0 + r) * 136 + n] = f2bf(acc[r]);
        }
      }
    }
    bar_lds();

    // ---- chunk 1: producers k n-tiles | consumers out-proj -> osr --------
    if (do_p) {
      prod_task<1>((wid >> 1) + 8,  xf, wqkvT, qw, kw, vw, ln15, quad, m_sub, mh);
      prod_task<1>((wid >> 1) + 12, xf, wqkvT, qw, kw, vw, ln15, quad, m_sub, mh);
    } else if (do_c) {
      const int mt5 = cwid >> 1, nh = cwid & 1;
      s16x8 af[4];
#pragma unroll
      for (int ks = 0; ks < 4; ++ks)
        af[ks] = *(const s16x8*)(oa_s + (mt5 * 16 + ln15) * 136 + ks * 32 + quad * 8);
#pragma unroll
      for (int nt = 0; nt < 4; ++nt) {
        int n = nh * 64 + nt * 16 + ln15;
        const unsigned short* wp = woutT + n * 128 + quad * 8;
        s16x8 bfr[4];
#pragma unroll
        for (int ks = 0; ks < 4; ++ks) bfr[ks] = *(const s16x8*)(wp + ks * 32);
        f32x4 acc = {0.f, 0.f, 0.f, 0.f};
#pragma unroll
        for (int ks = 0; ks < 4; ++ks) acc = mfma16(af[ks], bfr[ks], acc);
        float bo = b_out[n];
#pragma unroll
        for (int r = 0; r < 4; ++r)
          osr[(mt5 * 16 + m_sub + r) * 132 + n] = acc[r] + bo;
      }
    }
    bar_lds();

    // ---- chunk 2: producers v n-tiles | consumers coalesced stores -------
    if (do_p) {
      prod_task<2>((wid >> 1) + 16, xf, wqkvT, qw, kw, vw, ln15, quad, m_sub, mh);
      prod_task<2>((wid >> 1) + 20, xf, wqkvT, qw, kw, vw, ln15, quad, m_sub, mh);
    } else if (do_c) {
      float* outb = out + (long)b * BATCH_STRIDE;
#pragma unroll
      for (int k = 0; k < 4; ++k) {
        float4 o = *(const float4*)(osr + l6[k]);
        *(float4*)(outb + off6[k]) = o;
      }
    }
    bar_lds();
    wbuf = rbuf;
  }
}

extern "C" void kernel_launch(void* const* d_in, const int* in_sizes, int n_in,
                              void* d_out, int out_size, void* d_ws, size_t ws_size,
                              hipStream_t stream) {
  const float* x    = (const float*)d_in[0];
  const float* wqkv = (const float*)d_in[1];
  const float* wout = (const float*)d_in[2];
  const float* bout = (const float*)d_in[3];
  const float* pe   = (const float*)d_in[4];
  const float* ulm  = (const float*)d_in[5];
  const float* lrm  = (const float*)d_in[6];

  unsigned short* wqkvT = (unsigned short*)d_ws;           // 384*128 bf16
  unsigned short* woutT = wqkvT + 384 * 128;               // 128*128 bf16

  prep_weights<<<(384 * 128 + 128 * 128) / 256, 256, 0, stream>>>(wqkv, wout, wqkvT, woutT);
  swin_fused<<<256, 1024, 0, stream>>>(x, wqkvT, woutT, bout, pe, ulm, lrm,
                                       (float*)d_out);
}